// Round 6
// baseline (1474.389 us; speedup 1.0000x reference)
//
#include <hip/hip_runtime.h>
#include <cstdint>
#include <cstddef>

#define TLEN 512
#define BATCH 1000
#define NEVS 102400   // events per source
#define HID 64
#define W0S 16        // fused0 window steps per phase
#define NP (TLEN / W0S)

__device__ __forceinline__ float fast_rcp(float x) {
#if __has_builtin(__builtin_amdgcn_rcpf)
    return __builtin_amdgcn_rcpf(x);
#else
    return 1.0f / x;
#endif
}
__device__ __forceinline__ float sigm(float x) { return fast_rcp(1.0f + __expf(-x)); }
__device__ __forceinline__ float tanh_f(float x) { return fmaf(2.0f, sigm(2.0f * x), -1.0f); }

// Opaque pin: value becomes asm-defined -> compiler shouldn't sink/remat the load.
__device__ __forceinline__ void pin(float& x) { asm volatile("" : "+v"(x)); }

// Cross-lane launder: identity shuffle. The result is a convergent cross-lane
// op's output -> LLVM cannot rematerialize it by re-loading from memory, so
// the value MUST live in a register (or scratch, which would show as traffic).
// This is the strong form of "pin" (empty asm was defeated, rounds 4-5).
__device__ __forceinline__ float lane_pin(float x) {
    return __shfl(x, (int)(threadIdx.x & 63), 64);
}

// Wave-wide sum broadcast (rocPRIM gfx9 DPP pattern).
__device__ __forceinline__ float wave_sum_bcast(float x) {
#if __has_builtin(__builtin_amdgcn_update_dpp) && __has_builtin(__builtin_amdgcn_readlane)
    x += __int_as_float(__builtin_amdgcn_update_dpp(0, __float_as_int(x), 0x111, 0xf, 0xf, true)); // row_shr:1
    x += __int_as_float(__builtin_amdgcn_update_dpp(0, __float_as_int(x), 0x112, 0xf, 0xf, true)); // row_shr:2
    x += __int_as_float(__builtin_amdgcn_update_dpp(0, __float_as_int(x), 0x114, 0xf, 0xf, true)); // row_shr:4
    x += __int_as_float(__builtin_amdgcn_update_dpp(0, __float_as_int(x), 0x118, 0xf, 0xf, true)); // row_shr:8
    x += __int_as_float(__builtin_amdgcn_update_dpp(0, __float_as_int(x), 0x142, 0xa, 0xf, true)); // row_bcast:15
    x += __int_as_float(__builtin_amdgcn_update_dpp(0, __float_as_int(x), 0x143, 0xc, 0xf, true)); // row_bcast:31
    return __int_as_float(__builtin_amdgcn_readlane(__float_as_int(x), 63));
#else
#pragma unroll
    for (int off = 1; off < 64; off <<= 1) x += __shfl_xor(x, off, 64);
    return x;
#endif
}

// Two independent wave sums, stages interleaved for ILP.
__device__ __forceinline__ void wave_sum2(float& a, float& b) {
#if __has_builtin(__builtin_amdgcn_update_dpp) && __has_builtin(__builtin_amdgcn_readlane)
    int ta, tb;
    ta = __builtin_amdgcn_update_dpp(0, __float_as_int(a), 0x111, 0xf, 0xf, true);
    tb = __builtin_amdgcn_update_dpp(0, __float_as_int(b), 0x111, 0xf, 0xf, true);
    a += __int_as_float(ta); b += __int_as_float(tb);
    ta = __builtin_amdgcn_update_dpp(0, __float_as_int(a), 0x112, 0xf, 0xf, true);
    tb = __builtin_amdgcn_update_dpp(0, __float_as_int(b), 0x112, 0xf, 0xf, true);
    a += __int_as_float(ta); b += __int_as_float(tb);
    ta = __builtin_amdgcn_update_dpp(0, __float_as_int(a), 0x114, 0xf, 0xf, true);
    tb = __builtin_amdgcn_update_dpp(0, __float_as_int(b), 0x114, 0xf, 0xf, true);
    a += __int_as_float(ta); b += __int_as_float(tb);
    ta = __builtin_amdgcn_update_dpp(0, __float_as_int(a), 0x118, 0xf, 0xf, true);
    tb = __builtin_amdgcn_update_dpp(0, __float_as_int(b), 0x118, 0xf, 0xf, true);
    a += __int_as_float(ta); b += __int_as_float(tb);
    ta = __builtin_amdgcn_update_dpp(0, __float_as_int(a), 0x142, 0xa, 0xf, true);
    tb = __builtin_amdgcn_update_dpp(0, __float_as_int(b), 0x142, 0xa, 0xf, true);
    a += __int_as_float(ta); b += __int_as_float(tb);
    ta = __builtin_amdgcn_update_dpp(0, __float_as_int(a), 0x143, 0xc, 0xf, true);
    tb = __builtin_amdgcn_update_dpp(0, __float_as_int(b), 0x143, 0xc, 0xf, true);
    a += __int_as_float(ta); b += __int_as_float(tb);
    a = __int_as_float(__builtin_amdgcn_readlane(__float_as_int(a), 63));
    b = __int_as_float(__builtin_amdgcn_readlane(__float_as_int(b), 63));
#else
    a = wave_sum_bcast(a); b = wave_sum_bcast(b);
#endif
}

// ===========================================================================
// map[b*512+t] = src<<20 | e  (sources partition the (b,t) grid: exactly one)
// ===========================================================================
__global__ __launch_bounds__(256) void map_build_kernel(
    const int* __restrict__ b0, const int* __restrict__ t0,
    const int* __restrict__ b1, const int* __restrict__ t1,
    const int* __restrict__ b2, const int* __restrict__ t2,
    const int* __restrict__ b3, const int* __restrict__ t3,
    const int* __restrict__ b4, const int* __restrict__ t4,
    int* __restrict__ map)
{
    const int src = blockIdx.y;
    const int* bi = src == 0 ? b0 : src == 1 ? b1 : src == 2 ? b2 : src == 3 ? b3 : b4;
    const int* ti = src == 0 ? t0 : src == 1 ? t1 : src == 2 ? t2 : src == 3 ? t3 : t4;
    const int e = blockIdx.x * 256 + threadIdx.x;
    map[bi[e] * TLEN + ti[e]] = (src << 20) | e;
}

// ===========================================================================
// Composed projection weights: wp[row][col], row=(src,j) [130], col=dir*256+r.
// row j<IND: W_src[j] . Wih0[col]; row j==IND: b_src . Wih0[col] + bih+bhh.
// ===========================================================================
__global__ __launch_bounds__(512) void compose_kernel(
    const float* __restrict__ W0, const float* __restrict__ B0,
    const float* __restrict__ W1, const float* __restrict__ B1,
    const float* __restrict__ W2, const float* __restrict__ B2,
    const float* __restrict__ W3, const float* __restrict__ B3,
    const float* __restrict__ W4, const float* __restrict__ B4,
    const float* __restrict__ Wih, const float* __restrict__ bih,
    const float* __restrict__ bhh, float* __restrict__ wp)
{
    const int col = threadIdx.x;   // 0..511 == dir*256 + r == Wih row index
    const int row = blockIdx.x;    // 0..129
    const float* srcW; const float* srcB; int base, IND;
    if (row < 9)        { srcW = W0; srcB = B0; base = 0;   IND = 8;  }
    else if (row < 27)  { srcW = W1; srcB = B1; base = 9;   IND = 17; }
    else if (row < 53)  { srcW = W2; srcB = B2; base = 27;  IND = 25; }
    else if (row < 120) { srcW = W3; srcB = B3; base = 53;  IND = 66; }
    else                { srcW = W4; srcB = B4; base = 120; IND = 9;  }
    const int j = row - base;
    const float* xrow = (j < IND) ? (srcW + (size_t)j * 64) : srcB;
    const float* wr = Wih + (size_t)col * 64;
    float acc = 0.0f;
#pragma unroll
    for (int h2 = 0; h2 < 64; ++h2) acc = fmaf(xrow[h2], wr[h2], acc);
    if (j == IND) acc += bih[col] + bhh[col];
    wp[(size_t)row * 512 + col] = acc;
}

// ===========================================================================
// Fused layer-0, v4 = v3 + lane_pin launder + 256-VGPR cap.
// Block = (b,dir), 512 threads (8 waves); q = tid>>8 selects row-half.
// ===========================================================================
template<bool HI>
__device__ __forceinline__ void fused_path(
    const float* __restrict__ wp, const int* __restrict__ map,
    const float* __restrict__ ccba_num,
    const float* __restrict__ cdtx_num, const int* __restrict__ cdtx_cat, const float* __restrict__ cdtx_tab,
    const float* __restrict__ cust_num, const int* __restrict__ cust_cat, const float* __restrict__ cust_tab,
    const float* __restrict__ dp_num,   const int* __restrict__ dp_cat,   const float* __restrict__ dp_tab,
    const float* __restrict__ remit_num, const int* __restrict__ remit_cat, const float* __restrict__ remit_tab,
    const float* __restrict__ Whh, const float* __restrict__ Whr,
    float* __restrict__ h0, int b, int dir, int tid,
    float (&winP)[2][W0S][256], float (&xbuf)[2][W0S][68], int (&mcls)[2][W0S])
{
    // FMA row counts / offsets per source for this half.
    constexpr int C0 = HI ? 3 : 5,  O0 = HI ? 5 : 0;    // ccba  (9 rows)
    constexpr int C1 = HI ? 8 : 9,  O1 = HI ? 9 : 0;    // cdtx  (18)
    constexpr int C2 = HI ? 12 : 13, O2 = HI ? 13 : 0;  // cust  (26)
    constexpr int C3 = HI ? 32 : 34, O3 = HI ? 34 : 0;  // dp    (67)
    constexpr int C4 = HI ? 4 : 5,  O4 = HI ? 5 : 0;    // remit (10)

    const int pcol = tid & 255;
    const int col = dir * 256 + pcol;

    float w0[C0], w1[C1], w2[C2], w3[C3], w4[C4];
#pragma unroll
    for (int j = 0; j < C0; ++j) w0[j] = wp[(size_t)(0 + O0 + j) * 512 + col];
#pragma unroll
    for (int j = 0; j < C1; ++j) w1[j] = wp[(size_t)(9 + O1 + j) * 512 + col];
#pragma unroll
    for (int j = 0; j < C2; ++j) w2[j] = wp[(size_t)(27 + O2 + j) * 512 + col];
#pragma unroll
    for (int j = 0; j < C3; ++j) w3[j] = wp[(size_t)(53 + O3 + j) * 512 + col];
#pragma unroll
    for (int j = 0; j < C4; ++j) w4[j] = wp[(size_t)(120 + O4 + j) * 512 + col];
    float bias0 = 0, bias1 = 0, bias2 = 0, bias3 = 0, bias4 = 0;
    if (HI) {
        bias0 = wp[(size_t)8 * 512 + col];
        bias1 = wp[(size_t)26 * 512 + col];
        bias2 = wp[(size_t)52 * 512 + col];
        bias3 = wp[(size_t)119 * 512 + col];
        bias4 = wp[(size_t)129 * 512 + col];
    }
    // Launder every weight through an identity cross-lane op: result is a
    // convergent-op def, NOT a load -> cannot be remat'd by reloading.
#pragma unroll
    for (int j = 0; j < C0; ++j) { w0[j] = lane_pin(w0[j]); pin(w0[j]); }
#pragma unroll
    for (int j = 0; j < C1; ++j) { w1[j] = lane_pin(w1[j]); pin(w1[j]); }
#pragma unroll
    for (int j = 0; j < C2; ++j) { w2[j] = lane_pin(w2[j]); pin(w2[j]); }
#pragma unroll
    for (int j = 0; j < C3; ++j) { w3[j] = lane_pin(w3[j]); pin(w3[j]); }
#pragma unroll
    for (int j = 0; j < C4; ++j) { w4[j] = lane_pin(w4[j]); pin(w4[j]); }
    if (HI) {
        bias0 = lane_pin(bias0); bias1 = lane_pin(bias1); bias2 = lane_pin(bias2);
        bias3 = lane_pin(bias3); bias4 = lane_pin(bias4);
    }

    // Consumer state (only wave 0 of the q=0 path uses it).
    const int lane = tid & 63;
    float whh4[4] = {0, 0, 0, 0};
    float whr = 0.0f, h = 0.0f, c = 0.0f;
    if (!HI && tid < 64) {
#pragma unroll
        for (int k = 0; k < 4; ++k) whh4[k] = lane_pin(Whh[dir * 256 + k * 64 + lane]);
        whr = lane_pin(Whr[dir * HID + lane]);
    }
    float* h0p = h0 + (size_t)b * TLEN * 2 + dir;

    auto dot_evt = [&](int mc, const float* xb) -> float {
        const int src = mc >> 20;
        float a0 = 0.f, a1 = 0.f, bb = 0.f;
        switch (src) {
        case 0:
#pragma unroll
            for (int j = 0; j < C0; ++j) {
                if (j & 1) a1 = fmaf(xb[O0 + j], w0[j], a1); else a0 = fmaf(xb[O0 + j], w0[j], a0);
            }
            bb = bias0; break;
        case 1:
#pragma unroll
            for (int j = 0; j < C1; ++j) {
                if (j & 1) a1 = fmaf(xb[O1 + j], w1[j], a1); else a0 = fmaf(xb[O1 + j], w1[j], a0);
            }
            bb = bias1; break;
        case 2:
#pragma unroll
            for (int j = 0; j < C2; ++j) {
                if (j & 1) a1 = fmaf(xb[O2 + j], w2[j], a1); else a0 = fmaf(xb[O2 + j], w2[j], a0);
            }
            bb = bias2; break;
        case 3:
#pragma unroll
            for (int j = 0; j < C3; ++j) {
                if (j & 1) a1 = fmaf(xb[O3 + j], w3[j], a1); else a0 = fmaf(xb[O3 + j], w3[j], a0);
            }
            bb = bias3; break;
        default:
#pragma unroll
            for (int j = 0; j < C4; ++j) {
                if (j & 1) a1 = fmaf(xb[O4 + j], w4[j], a1); else a0 = fmaf(xb[O4 + j], w4[j], a0);
            }
            bb = bias4; break;
        }
        return HI ? (bb + a0 + a1) : (a0 + a1);
    };

    // A0: 32 threads per event gather its raw inputs into xbuf[slot].
    auto gather_phase = [&](int P, int slot) {
        const int ev = tid >> 5, v = tid & 31;   // 512 threads / 32 = 16 events
        const int s = P * W0S + ev;
        const int t = dir ? (TLEN - 1 - s) : s;
        const int mc = map[b * TLEN + t];
        if (v == 0) mcls[slot][ev] = mc;
        const int src = mc >> 20, e = mc & 0xFFFFF;
        switch (src) {
        case 0:
            if (v < 8) xbuf[slot][ev][v] = ccba_num[(size_t)e * 8 + v];
            break;
        case 1:
            if (v < 17) xbuf[slot][ev][v] = (v < 16)
                ? cdtx_tab[(size_t)cdtx_cat[e * 2 + (v >> 3)] * 8 + (v & 7)] : cdtx_num[e];
            break;
        case 2:
            if (v < 25) xbuf[slot][ev][v] = (v < 24)
                ? cust_tab[(size_t)cust_cat[e * 3 + (v >> 3)] * 8 + (v & 7)] : cust_num[e];
            break;
        case 3:
#pragma unroll
            for (int vv = v; vv < 66; vv += 32)
                xbuf[slot][ev][vv] = (vv < 64)
                    ? dp_tab[(size_t)dp_cat[e * 8 + (vv >> 3)] * 8 + (vv & 7)]
                    : dp_num[(size_t)e * 2 + (vv - 64)];
            break;
        default:
            if (v < 9) xbuf[slot][ev][v] = (v < 8)
                ? remit_tab[(size_t)remit_cat[e] * 8 + v] : remit_num[e];
            break;
        }
    };

    // A1: dot this phase's events against the resident half-rows.
    auto dots_phase = [&](int slot) {
#pragma unroll 1
        for (int sl = 0; sl < W0S; sl += 2) {
            const int mc0 = mcls[slot][sl];
            const int mc1 = mcls[slot][sl + 1];
            const float a = dot_evt(mc0, xbuf[slot][sl]);
            const float bq = dot_evt(mc1, xbuf[slot][sl + 1]);
            winP[HI ? 1 : 0][sl][pcol] = a;
            winP[HI ? 1 : 0][sl + 1][pcol] = bq;
        }
    };

    gather_phase(0, 0);
    __syncthreads();

    for (int p = 0; p < NP; ++p) {
        if (p + 1 < NP) gather_phase(p + 1, (p + 1) & 1);   // VMEM in flight under A1
        dots_phase(p & 1);
        __syncthreads();

        if (!HI && tid < 64) {
            float G0[4], G1[4];
#pragma unroll
            for (int k = 0; k < 4; ++k) {
                G0[k] = winP[0][0][k * 64 + lane];
                G1[k] = winP[1][0][k * 64 + lane];
            }
            for (int sl = 0; sl < W0S; ++sl) {
                const int sn = (sl + 1 < W0S) ? sl + 1 : sl;
                float N0[4], N1[4];
#pragma unroll
                for (int k = 0; k < 4; ++k) {
                    N0[k] = winP[0][sn][k * 64 + lane];
                    N1[k] = winP[1][sn][k * 64 + lane];
                }
                const float gi = fmaf(whh4[0], h, G0[0] + G1[0]);
                const float gf = fmaf(whh4[1], h, G0[1] + G1[1]);
                const float gg = fmaf(whh4[2], h, G0[2] + G1[2]);
                const float go = fmaf(whh4[3], h, G0[3] + G1[3]);
                c = sigm(gf) * c + sigm(gi) * tanh_f(gg);
                h = wave_sum_bcast(sigm(go) * tanh_f(c) * whr);
                const int s = p * W0S + sl;
                const int t = dir ? (TLEN - 1 - s) : s;
                if (lane == 0) h0p[(size_t)t * 2] = h;
#pragma unroll
                for (int k = 0; k < 4; ++k) { G0[k] = N0[k]; G1[k] = N1[k]; }
            }
        }
        __syncthreads();
    }
}

__global__ __launch_bounds__(512, 2) void fused0_kernel(
    const float* __restrict__ ccba_num,
    const float* __restrict__ cdtx_num, const int* __restrict__ cdtx_cat, const float* __restrict__ cdtx_tab,
    const float* __restrict__ cust_num, const int* __restrict__ cust_cat, const float* __restrict__ cust_tab,
    const float* __restrict__ dp_num,   const int* __restrict__ dp_cat,   const float* __restrict__ dp_tab,
    const float* __restrict__ remit_num, const int* __restrict__ remit_cat, const float* __restrict__ remit_tab,
    const float* __restrict__ wp, const int* __restrict__ map,
    const float* __restrict__ Whh, const float* __restrict__ Whr,
    float* __restrict__ h0)
{
    __shared__ float winP[2][W0S][256];
    __shared__ float xbuf[2][W0S][68];
    __shared__ int   mcls[2][W0S];
    const int tid = threadIdx.x;
    const int b = blockIdx.x >> 1, dir = blockIdx.x & 1;
    if (tid < 256)
        fused_path<false>(wp, map, ccba_num,
            cdtx_num, cdtx_cat, cdtx_tab, cust_num, cust_cat, cust_tab,
            dp_num, dp_cat, dp_tab, remit_num, remit_cat, remit_tab,
            Whh, Whr, h0, b, dir, tid, winP, xbuf, mcls);
    else
        fused_path<true>(wp, map, ccba_num,
            cdtx_num, cdtx_cat, cdtx_tab, cust_num, cust_cat, cust_tab,
            dp_num, dp_cat, dp_tab, remit_num, remit_cat, remit_tab,
            Whh, Whr, h0, b, dir, tid, winP, xbuf, mcls);
}

// ===========================================================================
// LSTM layer 1 (insz=2): one wave per b, BOTH dirs as two interleaved chains
// (independent serial chains -> 2x latency hiding). DPP paired reduce.
// Weights laundered (serial chain cannot hide re-load latency).
// ===========================================================================
__global__ __launch_bounds__(256, 2) void lstm1_kernel(
    const float* __restrict__ h0, const float* __restrict__ Wih,
    const float* __restrict__ Whh, const float* __restrict__ Whr,
    const float* __restrict__ bih, const float* __restrict__ bhh,
    float* __restrict__ h1)
{
    const int w = threadIdx.x >> 6, lane = threadIdx.x & 63;
    const int b = blockIdx.x * 4 + w;              // grid 250 -> b 0..999

    float wi0[2][4], wi1[2][4], whh[2][4], bias[2][4], whr[2];
#pragma unroll
    for (int d = 0; d < 2; ++d) {
#pragma unroll
        for (int k = 0; k < 4; ++k) {
            const int r = d * 256 + k * 64 + lane;
            wi0[d][k] = Wih[(size_t)r * 2 + 0];
            wi1[d][k] = Wih[(size_t)r * 2 + 1];
            whh[d][k] = Whh[r];
            bias[d][k] = bih[r] + bhh[r];
        }
        whr[d] = Whr[d * HID + lane];
    }
#pragma unroll
    for (int d = 0; d < 2; ++d) {
#pragma unroll
        for (int k = 0; k < 4; ++k) {
            wi0[d][k] = lane_pin(wi0[d][k]);
            wi1[d][k] = lane_pin(wi1[d][k]);
            whh[d][k] = lane_pin(whh[d][k]);
            bias[d][k] = lane_pin(bias[d][k]);
        }
        whr[d] = lane_pin(whr[d]);
    }
    float hA = 0, cA = 0, hB = 0, cB = 0;
    const float* hb = h0 + (size_t)b * TLEN * 2;

    float2 xA = *(const float2*)(hb);                          // fwd t=0
    float2 xB = *(const float2*)(hb + (size_t)(TLEN - 1) * 2); // bwd t=511
    for (int t = 0; t < TLEN; ++t) {
        const int tn = (t + 1 < TLEN) ? t + 1 : t;
        const float2 xAn = *(const float2*)(hb + (size_t)tn * 2);
        const float2 xBn = *(const float2*)(hb + (size_t)(TLEN - 1 - tn) * 2);
        float gA[4], gB[4];
#pragma unroll
        for (int k = 0; k < 4; ++k) {
            gA[k] = fmaf(whh[0][k], hA, fmaf(wi1[0][k], xA.y, fmaf(wi0[0][k], xA.x, bias[0][k])));
            gB[k] = fmaf(whh[1][k], hB, fmaf(wi1[1][k], xB.y, fmaf(wi0[1][k], xB.x, bias[1][k])));
        }
        cA = sigm(gA[1]) * cA + sigm(gA[0]) * tanh_f(gA[2]);
        cB = sigm(gB[1]) * cB + sigm(gB[0]) * tanh_f(gB[2]);
        float pA = sigm(gA[3]) * tanh_f(cA) * whr[0];
        float pB = sigm(gB[3]) * tanh_f(cB) * whr[1];
        wave_sum2(pA, pB);
        hA = pA; hB = pB;
        if (lane == 0) {
            h1[((size_t)b * TLEN + t) * 2 + 0] = hA;
            h1[((size_t)b * TLEN + (TLEN - 1 - t)) * 2 + 1] = hB;
        }
        xA = xAn; xB = xBn;
    }
}

__global__ __launch_bounds__(256) void mean_kernel(
    const float2* __restrict__ h1, float* __restrict__ out)
{
    int i = blockIdx.x * 256 + threadIdx.x;
    if (i < BATCH * TLEN) {
        float2 v = h1[i];
        out[i] = 0.5f * (v.x + v.y);
    }
}

// ===========================================================================
extern "C" void kernel_launch(void* const* d_in, const int* in_sizes, int n_in,
                              void* d_out, int out_size, void* d_ws, size_t ws_size,
                              hipStream_t stream)
{
    const float* ccba_num = (const float*)d_in[0];
    const int*   ccba_bi  = (const int*)d_in[1];
    const int*   ccba_ti  = (const int*)d_in[2];
    const float* ccba_W   = (const float*)d_in[3];
    const float* ccba_b   = (const float*)d_in[4];
    const float* cdtx_num = (const float*)d_in[5];
    const int*   cdtx_cat = (const int*)d_in[6];
    const float* cdtx_tab = (const float*)d_in[7];
    const int*   cdtx_bi  = (const int*)d_in[8];
    const int*   cdtx_ti  = (const int*)d_in[9];
    const float* cdtx_W   = (const float*)d_in[10];
    const float* cdtx_b   = (const float*)d_in[11];
    const float* cust_num = (const float*)d_in[12];
    const int*   cust_cat = (const int*)d_in[13];
    const float* cust_tab = (const float*)d_in[14];
    const int*   cust_bi  = (const int*)d_in[15];
    const int*   cust_ti  = (const int*)d_in[16];
    const float* cust_W   = (const float*)d_in[17];
    const float* cust_b   = (const float*)d_in[18];
    const float* dp_num   = (const float*)d_in[19];
    const int*   dp_cat   = (const int*)d_in[20];
    const float* dp_tab   = (const float*)d_in[21];
    const int*   dp_bi    = (const int*)d_in[22];
    const int*   dp_ti    = (const int*)d_in[23];
    const float* dp_W     = (const float*)d_in[24];
    const float* dp_b     = (const float*)d_in[25];
    const float* remit_num = (const float*)d_in[26];
    const int*   remit_cat = (const int*)d_in[27];
    const float* remit_tab = (const float*)d_in[28];
    const int*   remit_bi  = (const int*)d_in[29];
    const int*   remit_ti  = (const int*)d_in[30];
    const float* remit_W   = (const float*)d_in[31];
    const float* remit_b   = (const float*)d_in[32];
    const float* Wih0 = (const float*)d_in[33];
    const float* Whh0 = (const float*)d_in[34];
    const float* Whr0 = (const float*)d_in[35];
    const float* bih0 = (const float*)d_in[36];
    const float* bhh0 = (const float*)d_in[37];
    const float* Wih1 = (const float*)d_in[38];
    const float* Whh1 = (const float*)d_in[39];
    const float* Whr1 = (const float*)d_in[40];
    const float* bih1 = (const float*)d_in[41];
    const float* bhh1 = (const float*)d_in[42];

    float* out = (float*)d_out;

    // Workspace: wp (266,240) | map (2,048,000) | h0 (4,096,000) | h1 (4,096,000)
    char* ws = (char*)d_ws;
    float* wp  = (float*)ws;
    int*   map = (int*)  (ws + 266240ull);
    float* h0  = (float*)(ws + 266240ull + 2048000ull);
    float* h1  = (float*)(ws + 266240ull + 2048000ull + 4096000ull);

    compose_kernel<<<130, 512, 0, stream>>>(
        ccba_W, ccba_b, cdtx_W, cdtx_b, cust_W, cust_b,
        dp_W, dp_b, remit_W, remit_b, Wih0, bih0, bhh0, wp);

    map_build_kernel<<<dim3(NEVS / 256, 5), 256, 0, stream>>>(
        ccba_bi, ccba_ti, cdtx_bi, cdtx_ti, cust_bi, cust_ti,
        dp_bi, dp_ti, remit_bi, remit_ti, map);

    fused0_kernel<<<2 * BATCH, 512, 0, stream>>>(
        ccba_num,
        cdtx_num, cdtx_cat, cdtx_tab,
        cust_num, cust_cat, cust_tab,
        dp_num, dp_cat, dp_tab,
        remit_num, remit_cat, remit_tab,
        wp, map, Whh0, Whr0, h0);

    lstm1_kernel<<<250, 256, 0, stream>>>(h0, Wih1, Whh1, Whr1, bih1, bhh1, h1);
    mean_kernel<<<(BATCH * TLEN + 255) / 256, 256, 0, stream>>>((const float2*)h1, out);
}

// Round 7
// 1459.087 us; speedup vs baseline: 1.0105x; 1.0105x over previous
//
#include <hip/hip_runtime.h>
#include <cstdint>
#include <cstddef>

#define TLEN 512
#define BATCH 1000
#define NEVS 102400   // events per source
#define HID 64
#define W0S 8         // steps per phase
#define NP (TLEN / W0S)

__device__ __forceinline__ float fast_rcp(float x) {
#if __has_builtin(__builtin_amdgcn_rcpf)
    return __builtin_amdgcn_rcpf(x);
#else
    return 1.0f / x;
#endif
}
__device__ __forceinline__ float sigm(float x) { return fast_rcp(1.0f + __expf(-x)); }
__device__ __forceinline__ float tanh_f(float x) { return fmaf(2.0f, sigm(2.0f * x), -1.0f); }

// Wave-wide sum broadcast (rocPRIM gfx9 DPP pattern).
__device__ __forceinline__ float wave_sum_bcast(float x) {
#if __has_builtin(__builtin_amdgcn_update_dpp) && __has_builtin(__builtin_amdgcn_readlane)
    x += __int_as_float(__builtin_amdgcn_update_dpp(0, __float_as_int(x), 0x111, 0xf, 0xf, true)); // row_shr:1
    x += __int_as_float(__builtin_amdgcn_update_dpp(0, __float_as_int(x), 0x112, 0xf, 0xf, true)); // row_shr:2
    x += __int_as_float(__builtin_amdgcn_update_dpp(0, __float_as_int(x), 0x114, 0xf, 0xf, true)); // row_shr:4
    x += __int_as_float(__builtin_amdgcn_update_dpp(0, __float_as_int(x), 0x118, 0xf, 0xf, true)); // row_shr:8
    x += __int_as_float(__builtin_amdgcn_update_dpp(0, __float_as_int(x), 0x142, 0xa, 0xf, true)); // row_bcast:15
    x += __int_as_float(__builtin_amdgcn_update_dpp(0, __float_as_int(x), 0x143, 0xc, 0xf, true)); // row_bcast:31
    return __int_as_float(__builtin_amdgcn_readlane(__float_as_int(x), 63));
#else
#pragma unroll
    for (int off = 1; off < 64; off <<= 1) x += __shfl_xor(x, off, 64);
    return x;
#endif
}

// Two independent wave sums, stages interleaved for ILP.
__device__ __forceinline__ void wave_sum2(float& a, float& b) {
#if __has_builtin(__builtin_amdgcn_update_dpp) && __has_builtin(__builtin_amdgcn_readlane)
    int ta, tb;
    ta = __builtin_amdgcn_update_dpp(0, __float_as_int(a), 0x111, 0xf, 0xf, true);
    tb = __builtin_amdgcn_update_dpp(0, __float_as_int(b), 0x111, 0xf, 0xf, true);
    a += __int_as_float(ta); b += __int_as_float(tb);
    ta = __builtin_amdgcn_update_dpp(0, __float_as_int(a), 0x112, 0xf, 0xf, true);
    tb = __builtin_amdgcn_update_dpp(0, __float_as_int(b), 0x112, 0xf, 0xf, true);
    a += __int_as_float(ta); b += __int_as_float(tb);
    ta = __builtin_amdgcn_update_dpp(0, __float_as_int(a), 0x114, 0xf, 0xf, true);
    tb = __builtin_amdgcn_update_dpp(0, __float_as_int(b), 0x114, 0xf, 0xf, true);
    a += __int_as_float(ta); b += __int_as_float(tb);
    ta = __builtin_amdgcn_update_dpp(0, __float_as_int(a), 0x118, 0xf, 0xf, true);
    tb = __builtin_amdgcn_update_dpp(0, __float_as_int(b), 0x118, 0xf, 0xf, true);
    a += __int_as_float(ta); b += __int_as_float(tb);
    ta = __builtin_amdgcn_update_dpp(0, __float_as_int(a), 0x142, 0xa, 0xf, true);
    tb = __builtin_amdgcn_update_dpp(0, __float_as_int(b), 0x142, 0xa, 0xf, true);
    a += __int_as_float(ta); b += __int_as_float(tb);
    ta = __builtin_amdgcn_update_dpp(0, __float_as_int(a), 0x143, 0xc, 0xf, true);
    tb = __builtin_amdgcn_update_dpp(0, __float_as_int(b), 0x143, 0xc, 0xf, true);
    a += __int_as_float(ta); b += __int_as_float(tb);
    a = __int_as_float(__builtin_amdgcn_readlane(__float_as_int(a), 63));
    b = __int_as_float(__builtin_amdgcn_readlane(__float_as_int(b), 63));
#else
    a = wave_sum_bcast(a); b = wave_sum_bcast(b);
#endif
}

// ===========================================================================
// map[b*512+t] = src<<20 | e  (sources partition the (b,t) grid: exactly one)
// ===========================================================================
__global__ __launch_bounds__(256) void map_build_kernel(
    const int* __restrict__ b0, const int* __restrict__ t0,
    const int* __restrict__ b1, const int* __restrict__ t1,
    const int* __restrict__ b2, const int* __restrict__ t2,
    const int* __restrict__ b3, const int* __restrict__ t3,
    const int* __restrict__ b4, const int* __restrict__ t4,
    int* __restrict__ map)
{
    const int src = blockIdx.y;
    const int* bi = src == 0 ? b0 : src == 1 ? b1 : src == 2 ? b2 : src == 3 ? b3 : b4;
    const int* ti = src == 0 ? t0 : src == 1 ? t1 : src == 2 ? t2 : src == 3 ? t3 : t4;
    const int e = blockIdx.x * 256 + threadIdx.x;
    map[bi[e] * TLEN + ti[e]] = (src << 20) | e;
}

// ===========================================================================
// Composed projection weights: wp[row][col], row=(src,j) [130], col=dir*256+r.
// row j<IND: W_src[j] . Wih0[col]; row j==IND: b_src . Wih0[col] + bih+bhh.
// ===========================================================================
__global__ __launch_bounds__(512) void compose_kernel(
    const float* __restrict__ W0, const float* __restrict__ B0,
    const float* __restrict__ W1, const float* __restrict__ B1,
    const float* __restrict__ W2, const float* __restrict__ B2,
    const float* __restrict__ W3, const float* __restrict__ B3,
    const float* __restrict__ W4, const float* __restrict__ B4,
    const float* __restrict__ Wih, const float* __restrict__ bih,
    const float* __restrict__ bhh, float* __restrict__ wp)
{
    const int col = threadIdx.x;   // 0..511 == dir*256 + r == Wih row index
    const int row = blockIdx.x;    // 0..129
    const float* srcW; const float* srcB; int base, IND;
    if (row < 9)        { srcW = W0; srcB = B0; base = 0;   IND = 8;  }
    else if (row < 27)  { srcW = W1; srcB = B1; base = 9;   IND = 17; }
    else if (row < 53)  { srcW = W2; srcB = B2; base = 27;  IND = 25; }
    else if (row < 120) { srcW = W3; srcB = B3; base = 53;  IND = 66; }
    else                { srcW = W4; srcB = B4; base = 120; IND = 9;  }
    const int j = row - base;
    const float* xrow = (j < IND) ? (srcW + (size_t)j * 64) : srcB;
    const float* wr = Wih + (size_t)col * 64;
    float acc = 0.0f;
#pragma unroll
    for (int h2 = 0; h2 < 64; ++h2) acc = fmaf(xrow[h2], wr[h2], acc);
    if (j == IND) acc += bih[col] + bhh[col];
    wp[(size_t)row * 512 + col] = acc;
}

// ===========================================================================
// dot4: event x over a source's padded row range against LDS weights.
// Wave = one event -> w reads are full-row contiguous b128 (conflict-free),
// x reads are uniform (broadcast). 16 FMA per 5 LDS ops.
// ===========================================================================
template<int NB, int BASE>
__device__ __forceinline__ float4 dot4(const float* wT, const float* xb, int colq) {
    float ax = 0.f, ay = 0.f, az = 0.f, aw = 0.f;
#pragma unroll
    for (int jb = 0; jb < NB; ++jb) {
        const float4 x4 = *(const float4*)(xb + 4 * jb);
        const float* w = wT + (size_t)(BASE + 4 * jb) * 256 + 4 * colq;
        const float4 w0 = *(const float4*)(w);
        const float4 w1 = *(const float4*)(w + 256);
        const float4 w2 = *(const float4*)(w + 512);
        const float4 w3 = *(const float4*)(w + 768);
        ax = fmaf(x4.x, w0.x, ax); ay = fmaf(x4.x, w0.y, ay);
        az = fmaf(x4.x, w0.z, az); aw = fmaf(x4.x, w0.w, aw);
        ax = fmaf(x4.y, w1.x, ax); ay = fmaf(x4.y, w1.y, ay);
        az = fmaf(x4.y, w1.z, az); aw = fmaf(x4.y, w1.w, aw);
        ax = fmaf(x4.z, w2.x, ax); ay = fmaf(x4.z, w2.y, ay);
        az = fmaf(x4.z, w2.z, az); aw = fmaf(x4.z, w2.w, aw);
        ax = fmaf(x4.w, w3.x, ax); ay = fmaf(x4.w, w3.y, ay);
        az = fmaf(x4.w, w3.z, az); aw = fmaf(x4.w, w3.w, aw);
    }
    return make_float4(ax, ay, az, aw);
}

// ===========================================================================
// Fused layer-0, v5: weights in LDS (no per-thread residency requirement).
// Block = (b,dir), 576 threads: 8 producer waves (wave = event) + 1 consumer
// wave. 3-stage pipeline: gather(p+2) || A1(p+1) || recurrence B(p).
// LDS: wT 135.2K + winP 8K*2 + xbuf 2.2K*2 + mcls = ~156 KB (1 block/CU).
// ===========================================================================
__global__ __launch_bounds__(576, 1) void fused0_kernel(
    const float* __restrict__ ccba_num,
    const float* __restrict__ cdtx_num, const int* __restrict__ cdtx_cat, const float* __restrict__ cdtx_tab,
    const float* __restrict__ cust_num, const int* __restrict__ cust_cat, const float* __restrict__ cust_tab,
    const float* __restrict__ dp_num,   const int* __restrict__ dp_cat,   const float* __restrict__ dp_tab,
    const float* __restrict__ remit_num, const int* __restrict__ remit_cat, const float* __restrict__ remit_tab,
    const float* __restrict__ wp, const int* __restrict__ map,
    const float* __restrict__ Whh, const float* __restrict__ Whr,
    float* __restrict__ h0)
{
    __shared__ float wT[132 * 256];          // [row][col], rows 130/131 zeroed
    __shared__ float winP[2][W0S][256];
    __shared__ float xbuf[2][W0S][68];       // padded x (bias=1.0 folded in)
    __shared__ int   mcls[2][W0S];

    const int tid = threadIdx.x;
    const int b = blockIdx.x >> 1, dir = blockIdx.x & 1;

    // ---- stage weights: this dir's 256-col half of every row ----
    {
        const float4* wp4 = (const float4*)wp;   // 130 rows x 128 float4
        float4* wT4 = (float4*)wT;
        for (int i = tid; i < 130 * 64; i += 576) {
            const int row = i >> 6, c4 = i & 63;
            wT4[(row << 6) + c4] = wp4[(row << 7) + (dir << 6) + c4];
        }
        if (tid < 128) wT4[130 * 64 + tid] = make_float4(0.f, 0.f, 0.f, 0.f);
    }

    // ---- consumer state (wave 8) ----
    float whh4[4] = {0.f, 0.f, 0.f, 0.f};
    float whr = 0.f, h = 0.f, c = 0.f;
    float* h0p = h0 + (size_t)b * TLEN * 2 + dir;
    if (tid >= 512) {
        const int lane = tid - 512;
#pragma unroll
        for (int k = 0; k < 4; ++k) whh4[k] = Whh[dir * 256 + k * 64 + lane];
        whr = Whr[dir * HID + lane];
    }

    struct GR { float v0, v1; int mc; };

    // gather: wave = one event, lane v loads one padded-x value.
    auto g_load = [&](int P) -> GR {
        GR g; g.v0 = 0.f; g.v1 = 0.f;
        const int ev = tid >> 6, v = tid & 63;
        const int s = P * W0S + ev;
        const int t = dir ? (TLEN - 1 - s) : s;
        g.mc = map[b * TLEN + t];
        const int src = g.mc >> 20, e = g.mc & 0xFFFFF;
        switch (src) {
        case 0:
            g.v0 = (v < 8) ? ccba_num[(size_t)e * 8 + v] : (v == 8 ? 1.0f : 0.0f);
            break;
        case 1:
            g.v0 = (v < 16) ? cdtx_tab[(size_t)cdtx_cat[e * 2 + (v >> 3)] * 8 + (v & 7)]
                 : (v == 16 ? cdtx_num[e] : (v == 17 ? 1.0f : 0.0f));
            break;
        case 2:
            g.v0 = (v < 24) ? cust_tab[(size_t)cust_cat[e * 3 + (v >> 3)] * 8 + (v & 7)]
                 : (v == 24 ? cust_num[e] : (v == 25 ? 1.0f : 0.0f));
            break;
        case 3:
            g.v0 = dp_tab[(size_t)dp_cat[e * 8 + (v >> 3)] * 8 + (v & 7)];
            if (v < 4) g.v1 = (v < 2) ? dp_num[(size_t)e * 2 + v] : (v == 2 ? 1.0f : 0.0f);
            break;
        default:
            g.v0 = (v < 8) ? remit_tab[(size_t)remit_cat[e] * 8 + v]
                 : (v == 8 ? remit_num[e] : (v == 9 ? 1.0f : 0.0f));
            break;
        }
        return g;
    };
    auto g_store = [&](const GR& g, int P) {
        const int buf = P & 1;
        const int ev = tid >> 6, v = tid & 63;
        if (v == 0) mcls[buf][ev] = g.mc;
        const int src = g.mc >> 20;
        const int pad = (src == 0) ? 12 : (src == 1) ? 20 : (src == 2) ? 28
                      : (src == 3) ? 64 : 12;
        if (v < pad) xbuf[buf][ev][v] = g.v0;
        if (src == 3 && v < 4) xbuf[buf][ev][64 + v] = g.v1;
    };

    // A1: thread = (event, col-quad); wave-uniform source branch.
    auto a1 = [&](int P) {
        const int buf = P & 1;
        const int ev = tid >> 6, colq = tid & 63;
        const int src = mcls[buf][ev] >> 20;
        const float* xb = xbuf[buf][ev];
        float4 acc;
        switch (src) {
        case 0:  acc = dot4<3, 0>(wT, xb, colq);   break;
        case 1:  acc = dot4<5, 9>(wT, xb, colq);   break;
        case 2:  acc = dot4<7, 27>(wT, xb, colq);  break;
        case 3:  acc = dot4<17, 53>(wT, xb, colq); break;
        default: acc = dot4<3, 120>(wT, xb, colq); break;
        }
        ((float4*)winP[buf][ev])[colq] = acc;
    };

    // B: consumer wave runs W0S recurrence steps for phase P.
    auto bstep = [&](int P) {
        const int buf = P & 1;
        const int lane = tid - 512;
        for (int sl = 0; sl < W0S; ++sl) {
            const float gi = fmaf(whh4[0], h, winP[buf][sl][lane]);
            const float gf = fmaf(whh4[1], h, winP[buf][sl][64 + lane]);
            const float gg = fmaf(whh4[2], h, winP[buf][sl][128 + lane]);
            const float go = fmaf(whh4[3], h, winP[buf][sl][192 + lane]);
            c = sigm(gf) * c + sigm(gi) * tanh_f(gg);
            h = wave_sum_bcast(sigm(go) * tanh_f(c) * whr);
            const int s = P * W0S + sl;
            const int tt = dir ? (TLEN - 1 - s) : s;
            if (lane == 0) h0p[(size_t)tt * 2] = h;
        }
    };

    // ---- prologue ----
    if (tid < 512) { GR g0 = g_load(0); g_store(g0, 0); }
    __syncthreads();                      // wT + xbuf[0] ready
    if (tid < 512) { GR g1 = g_load(1); a1(0); g_store(g1, 1); }
    __syncthreads();                      // winP[0] + xbuf[1] ready

    // ---- main loop: gather(p+2) || A1(p+1) || B(p) ----
    for (int p = 0; p < NP; ++p) {
        if (tid < 512) {
            GR g{};
            const bool hg = (p + 2 < NP);
            if (hg) g = g_load(p + 2);
            if (p + 1 < NP) a1(p + 1);
            if (hg) g_store(g, p + 2);
        } else if (tid < 576) {
            bstep(p);
        }
        __syncthreads();
    }
}

// ===========================================================================
// LSTM layer 1 (insz=2): one wave per b, BOTH dirs as two interleaved chains.
// Weights loaded VOLATILE: a volatile load is non-duplicable -> the compiler
// cannot re-materialize it inside the serial loop (rounds 4-6: every other
// pin was defeated; VGPR=20 meant 26 reloads/step on the critical chain).
// ===========================================================================
__global__ __launch_bounds__(256, 2) void lstm1_kernel(
    const float* __restrict__ h0, const float* __restrict__ Wih,
    const float* __restrict__ Whh, const float* __restrict__ Whr,
    const float* __restrict__ bih, const float* __restrict__ bhh,
    float* __restrict__ h1)
{
    const int w = threadIdx.x >> 6, lane = threadIdx.x & 63;
    const int b = blockIdx.x * 4 + w;              // grid 250 -> b 0..999

    const volatile float* vWih = Wih;
    const volatile float* vWhh = Whh;
    const volatile float* vWhr = Whr;
    const volatile float* vbih = bih;
    const volatile float* vbhh = bhh;

    float wi0[2][4], wi1[2][4], whh[2][4], bias[2][4], whr[2];
#pragma unroll
    for (int d = 0; d < 2; ++d) {
#pragma unroll
        for (int k = 0; k < 4; ++k) {
            const int r = d * 256 + k * 64 + lane;
            wi0[d][k] = vWih[(size_t)r * 2 + 0];
            wi1[d][k] = vWih[(size_t)r * 2 + 1];
            whh[d][k] = vWhh[r];
            bias[d][k] = vbih[r] + vbhh[r];
        }
        whr[d] = vWhr[d * HID + lane];
    }
    float hA = 0, cA = 0, hB = 0, cB = 0;
    const float* hb = h0 + (size_t)b * TLEN * 2;

    float2 xA = *(const float2*)(hb);                          // fwd t=0
    float2 xB = *(const float2*)(hb + (size_t)(TLEN - 1) * 2); // bwd t=511
    for (int t = 0; t < TLEN; ++t) {
        const int tn = (t + 1 < TLEN) ? t + 1 : t;
        const float2 xAn = *(const float2*)(hb + (size_t)tn * 2);
        const float2 xBn = *(const float2*)(hb + (size_t)(TLEN - 1 - tn) * 2);
        float gA[4], gB[4];
#pragma unroll
        for (int k = 0; k < 4; ++k) {
            gA[k] = fmaf(whh[0][k], hA, fmaf(wi1[0][k], xA.y, fmaf(wi0[0][k], xA.x, bias[0][k])));
            gB[k] = fmaf(whh[1][k], hB, fmaf(wi1[1][k], xB.y, fmaf(wi0[1][k], xB.x, bias[1][k])));
        }
        cA = sigm(gA[1]) * cA + sigm(gA[0]) * tanh_f(gA[2]);
        cB = sigm(gB[1]) * cB + sigm(gB[0]) * tanh_f(gB[2]);
        float pA = sigm(gA[3]) * tanh_f(cA) * whr[0];
        float pB = sigm(gB[3]) * tanh_f(cB) * whr[1];
        wave_sum2(pA, pB);
        hA = pA; hB = pB;
        if (lane == 0) {
            h1[((size_t)b * TLEN + t) * 2 + 0] = hA;
            h1[((size_t)b * TLEN + (TLEN - 1 - t)) * 2 + 1] = hB;
        }
        xA = xAn; xB = xBn;
    }
}

__global__ __launch_bounds__(256) void mean_kernel(
    const float2* __restrict__ h1, float* __restrict__ out)
{
    int i = blockIdx.x * 256 + threadIdx.x;
    if (i < BATCH * TLEN) {
        float2 v = h1[i];
        out[i] = 0.5f * (v.x + v.y);
    }
}

// ===========================================================================
extern "C" void kernel_launch(void* const* d_in, const int* in_sizes, int n_in,
                              void* d_out, int out_size, void* d_ws, size_t ws_size,
                              hipStream_t stream)
{
    const float* ccba_num = (const float*)d_in[0];
    const int*   ccba_bi  = (const int*)d_in[1];
    const int*   ccba_ti  = (const int*)d_in[2];
    const float* ccba_W   = (const float*)d_in[3];
    const float* ccba_b   = (const float*)d_in[4];
    const float* cdtx_num = (const float*)d_in[5];
    const int*   cdtx_cat = (const int*)d_in[6];
    const float* cdtx_tab = (const float*)d_in[7];
    const int*   cdtx_bi  = (const int*)d_in[8];
    const int*   cdtx_ti  = (const int*)d_in[9];
    const float* cdtx_W   = (const float*)d_in[10];
    const float* cdtx_b   = (const float*)d_in[11];
    const float* cust_num = (const float*)d_in[12];
    const int*   cust_cat = (const int*)d_in[13];
    const float* cust_tab = (const float*)d_in[14];
    const int*   cust_bi  = (const int*)d_in[15];
    const int*   cust_ti  = (const int*)d_in[16];
    const float* cust_W   = (const float*)d_in[17];
    const float* cust_b   = (const float*)d_in[18];
    const float* dp_num   = (const float*)d_in[19];
    const int*   dp_cat   = (const int*)d_in[20];
    const float* dp_tab   = (const float*)d_in[21];
    const int*   dp_bi    = (const int*)d_in[22];
    const int*   dp_ti    = (const int*)d_in[23];
    const float* dp_W     = (const float*)d_in[24];
    const float* dp_b     = (const float*)d_in[25];
    const float* remit_num = (const float*)d_in[26];
    const int*   remit_cat = (const int*)d_in[27];
    const float* remit_tab = (const float*)d_in[28];
    const int*   remit_bi  = (const int*)d_in[29];
    const int*   remit_ti  = (const int*)d_in[30];
    const float* remit_W   = (const float*)d_in[31];
    const float* remit_b   = (const float*)d_in[32];
    const float* Wih0 = (const float*)d_in[33];
    const float* Whh0 = (const float*)d_in[34];
    const float* Whr0 = (const float*)d_in[35];
    const float* bih0 = (const float*)d_in[36];
    const float* bhh0 = (const float*)d_in[37];
    const float* Wih1 = (const float*)d_in[38];
    const float* Whh1 = (const float*)d_in[39];
    const float* Whr1 = (const float*)d_in[40];
    const float* bih1 = (const float*)d_in[41];
    const float* bhh1 = (const float*)d_in[42];

    float* out = (float*)d_out;

    // Workspace: wp (266,240) | map (2,048,000) | h0 (4,096,000) | h1 (4,096,000)
    char* ws = (char*)d_ws;
    float* wp  = (float*)ws;
    int*   map = (int*)  (ws + 266240ull);
    float* h0  = (float*)(ws + 266240ull + 2048000ull);
    float* h1  = (float*)(ws + 266240ull + 2048000ull + 4096000ull);

    compose_kernel<<<130, 512, 0, stream>>>(
        ccba_W, ccba_b, cdtx_W, cdtx_b, cust_W, cust_b,
        dp_W, dp_b, remit_W, remit_b, Wih0, bih0, bhh0, wp);

    map_build_kernel<<<dim3(NEVS / 256, 5), 256, 0, stream>>>(
        ccba_bi, ccba_ti, cdtx_bi, cdtx_ti, cust_bi, cust_ti,
        dp_bi, dp_ti, remit_bi, remit_ti, map);

    fused0_kernel<<<2 * BATCH, 576, 0, stream>>>(
        ccba_num,
        cdtx_num, cdtx_cat, cdtx_tab,
        cust_num, cust_cat, cust_tab,
        dp_num, dp_cat, dp_tab,
        remit_num, remit_cat, remit_tab,
        wp, map, Whh0, Whr0, h0);

    lstm1_kernel<<<250, 256, 0, stream>>>(h0, Wih1, Whh1, Whr1, bih1, bhh1, h1);
    mean_kernel<<<(BATCH * TLEN + 255) / 256, 256, 0, stream>>>((const float2*)h1, out);
}